// Round 1
// baseline (327.269 us; speedup 1.0000x reference)
//
#include <hip/hip_runtime.h>
#include <math.h>

// ---------------- constants ----------------
// N=100 nodes, IN_C=65536, OUT_C=60, K=3 cheb, 2 heads, 1600 edges
#define KDIM    65536
#define NNODES  100
#define OUTC    60
#define KSPLIT  64          // K-chunks of 1024
#define MP      112         // 7 m-tiles of 16
#define NP      64          // 4 n-tiles of 16
#define SLAB    (MP*NP)     // 7168 floats per (kc,hk) partial

// ws layout (float offsets)
#define WS_S    0           // 10000
#define WS_Y    10048       // 6*7168 = 43008
#define WS_E    53248       // 2*6000 = 12000
#define WS_P    65536       // 384*7168 = 2752512

typedef short bf16x8 __attribute__((ext_vector_type(8)));
typedef float f32x4  __attribute__((ext_vector_type(4)));

__device__ inline short f2bf(float f) {
    union { float f; unsigned u; } x; x.f = f;
    unsigned r = x.u + 0x7FFFu + ((x.u >> 16) & 1u);   // RNE (finite inputs)
    return (short)(r >> 16);
}

// ---------------- kernel 1: build dense S = -D^-1/2 A D^-1/2 (scatter at dst) ----
__global__ __launch_bounds__(256) void k_build_s(const int* __restrict__ ei,
                                                 float* __restrict__ S) {
    __shared__ int   deg[NNODES];
    __shared__ float dinv[NNODES];
    const int t = threadIdx.x;
    if (t < NNODES) deg[t] = 0;
    for (int i = t; i < NNODES * NNODES; i += 256) S[i] = 0.f;
    __syncthreads();
    const int* src = ei;
    const int* dst = ei + 1600;
    for (int e = t; e < 1600; e += 256) atomicAdd(&deg[src[e]], 1);
    __syncthreads();
    if (t < NNODES) { int d = deg[t]; dinv[t] = (d > 0) ? rsqrtf((float)d) : 0.f; }
    __syncthreads();
    for (int e = t; e < 1600; e += 256) {
        int s = src[e], d = dst[e];
        atomicAdd(&S[d * NNODES + s], -dinv[s] * dinv[d]);
    }
}

// ---------------- kernel 2: split-K bf16 MFMA GEMM  Y_part = x @ W ----------------
// grid (6, 64): x = hk (head*3+k), y = K-chunk. block 256 = 4 waves, wave = n-tile.
__global__ __launch_bounds__(256) void k_gemm(const float* __restrict__ x,
                                              const float* __restrict__ wa,
                                              const float* __restrict__ wc,
                                              float* __restrict__ P) {
    const int hk   = blockIdx.x;
    const int kc   = blockIdx.y;
    const int wave = threadIdx.x >> 6;
    const int lane = threadIdx.x & 63;
    const int n16  = lane & 15;
    const int quad = lane >> 4;

    const float* W = (hk < 3 ? wa : wc) + (size_t)(hk % 3) * ((size_t)KDIM * OUTC);
    const int c0   = wave * 16;
    const int cidx = min(c0 + n16, OUTC - 1);     // clamp: cols 60..63 are junk

    int rowoff[7];
#pragma unroll
    for (int t = 0; t < 7; ++t) rowoff[t] = min(n16 + 16 * t, NNODES - 1) * KDIM;

    f32x4 acc[7] = {};
    const int kb0 = kc * 1024 + quad * 8;

    for (int s = 0; s < 32; ++s) {
        const int kb = kb0 + s * 32;              // this lane's k-base (incl quad*8)
        // B fragment: W[kb+j][cidx], j=0..7 (stride 60 floats)
        const float* bp = W + (size_t)kb * OUTC + cidx;
        bf16x8 bfr;
#pragma unroll
        for (int j = 0; j < 8; ++j) bfr[j] = f2bf(bp[(size_t)j * OUTC]);
        // A fragments: x[row][kb .. kb+8), contiguous
#pragma unroll
        for (int t = 0; t < 7; ++t) {
            const float* ap = x + rowoff[t] + kb;
            float4 lo = *(const float4*)ap;
            float4 hi = *(const float4*)(ap + 4);
            bf16x8 afr;
            afr[0] = f2bf(lo.x); afr[1] = f2bf(lo.y);
            afr[2] = f2bf(lo.z); afr[3] = f2bf(lo.w);
            afr[4] = f2bf(hi.x); afr[5] = f2bf(hi.y);
            afr[6] = f2bf(hi.z); afr[7] = f2bf(hi.w);
            acc[t] = __builtin_amdgcn_mfma_f32_16x16x32_bf16(afr, bfr, acc[t], 0, 0, 0);
        }
    }
    // D layout: col = lane&15, row = quad*4 + r (within 16x16 tile t)
    float* Pb = P + ((size_t)kc * 6 + hk) * SLAB;
#pragma unroll
    for (int t = 0; t < 7; ++t)
#pragma unroll
        for (int r = 0; r < 4; ++r) {
            int row = t * 16 + quad * 4 + r;
            Pb[row * NP + c0 + n16] = acc[t][r];
        }
}

// ---------------- kernel 3: reduce K-split partials -> Y[6][7168] ----------------
__global__ __launch_bounds__(256) void k_reduce(const float* __restrict__ P,
                                                float* __restrict__ Y) {
    const int g  = blockIdx.x * 256 + threadIdx.x;   // exactly 43008 threads
    const int hk = g / SLAB, q = g % SLAB;
    float s = 0.f;
#pragma unroll 8
    for (int kc = 0; kc < KSPLIT; ++kc) s += P[((size_t)kc * 6 + hk) * SLAB + q];
    Y[g] = s;
}

// ---------------- kernel 4: emb = tanh(Y0 + S Y1 + 2 S(S Y2) - Y2 + b) + vnr ------
// grid 120 = (head 2) x (col 60). 128 threads, thread n handles node n.
__global__ __launch_bounds__(128) void k_emb(const float* __restrict__ S,
                                             const float* __restrict__ Y,
                                             const float* __restrict__ vnr,
                                             const float* __restrict__ avw,
                                             const float* __restrict__ avb,
                                             const float* __restrict__ cvw,
                                             const float* __restrict__ cvb,
                                             const float* __restrict__ acb,
                                             const float* __restrict__ ccb,
                                             const float* __restrict__ afcb,
                                             const float* __restrict__ cfcb,
                                             float* __restrict__ E,
                                             float* __restrict__ out) {
    __shared__ float Sp[NNODES * 101];    // +1 pad: conflict-free row reads
    __shared__ float y0[NNODES], y1[NNODES], y2[NNODES], t2[NNODES];
    const int b = blockIdx.x, head = b / OUTC, c = b % OUTC;
    const int t = threadIdx.x;

    for (int i = t; i < NNODES * NNODES; i += 128)
        Sp[(i / NNODES) * 101 + (i % NNODES)] = S[i];
    const float* Yh = Y + (size_t)head * 3 * SLAB;
    if (t < NNODES) {
        y0[t] = Yh[t * NP + c];
        y1[t] = Yh[SLAB + t * NP + c];
        y2[t] = Yh[2 * SLAB + t * NP + c];
    }
    if (b == 0 && t < 101) out[t] = (t < 100) ? afcb[t] : cfcb[0];  // seed with biases
    __syncthreads();

    float z1 = 0.f, s2 = 0.f;
    if (t < NNODES) {
        const float* sr = Sp + t * 101;
        for (int m = 0; m < NNODES; ++m) { z1 += sr[m] * y1[m]; s2 += sr[m] * y2[m]; }
        t2[t] = s2;
    }
    __syncthreads();
    if (t < NNODES) {
        const float* sr = Sp + t * 101;
        float t3 = 0.f;
        for (int m = 0; m < NNODES; ++m) t3 += sr[m] * t2[m];
        const float* cb = head ? ccb : acb;
        const float* vw = head ? cvw : avw;
        const float* vb = head ? cvb : avb;
        float u  = y0[t] + z1 + 2.f * t3 - y2[t] + cb[c];
        float vs = vnr[0] * vw[c]        + vb[c]
                 + vnr[1] * vw[OUTC + c] + vb[OUTC + c]
                 + vnr[2] * vw[2*OUTC+c] + vb[2*OUTC+c];
        E[head * (NNODES * OUTC) + t * OUTC + c] = tanhf(u) + vs;
    }
}

// ---------------- kernel 5: heads: logits += flat_a @ afw ; value += flat_c @ cfw --
// grid 24 blocks x 250 flat indices each; d_out pre-seeded with biases by k_emb.
__global__ __launch_bounds__(128) void k_heads(const float* __restrict__ E,
                                               const float* __restrict__ afw,
                                               const float* __restrict__ cfw,
                                               float* __restrict__ out) {
    __shared__ float ea[250], ec[250];
    const int b = blockIdx.x, t = threadIdx.x;
    const int f0 = b * 250;
    for (int i = t; i < 250; i += 128) {
        ea[i] = E[f0 + i];
        ec[i] = E[NNODES * OUTC + f0 + i];
    }
    __syncthreads();
    if (t < 100) {
        float s = 0.f;
        for (int i = 0; i < 250; ++i) s += ea[i] * afw[(size_t)(f0 + i) * 100 + t];
        atomicAdd(&out[t], s);
    } else {
        float s = 0.f;
        for (int i = t - 100; i < 250; i += 28) s += ec[i] * cfw[f0 + i];
        atomicAdd(&out[100], s);
    }
}

// ---------------- launch ----------------
extern "C" void kernel_launch(void* const* d_in, const int* in_sizes, int n_in,
                              void* d_out, int out_size, void* d_ws, size_t ws_size,
                              hipStream_t stream) {
    const float* x    = (const float*)d_in[0];
    const int*   ei   = (const int*)  d_in[1];
    const float* vnr  = (const float*)d_in[2];
    const float* wa   = (const float*)d_in[3];
    const float* acb  = (const float*)d_in[4];
    const float* wc   = (const float*)d_in[5];
    const float* ccb  = (const float*)d_in[6];
    const float* avw  = (const float*)d_in[7];
    const float* avb  = (const float*)d_in[8];
    const float* cvw  = (const float*)d_in[9];
    const float* cvb  = (const float*)d_in[10];
    const float* afw  = (const float*)d_in[11];
    const float* afcb = (const float*)d_in[12];
    const float* cfw  = (const float*)d_in[13];
    const float* cfcb = (const float*)d_in[14];

    float* ws = (float*)d_ws;
    float* S  = ws + WS_S;
    float* Y  = ws + WS_Y;
    float* E  = ws + WS_E;
    float* P  = ws + WS_P;
    float* out = (float*)d_out;

    k_build_s<<<1, 256, 0, stream>>>(ei, S);
    k_gemm<<<dim3(6, KSPLIT), 256, 0, stream>>>(x, wa, wc, P);
    k_reduce<<<168, 256, 0, stream>>>(P, Y);
    k_emb<<<120, 128, 0, stream>>>(S, Y, vnr, avw, avb, cvw, cvb,
                                   acb, ccb, afcb, cfcb, E, out);
    k_heads<<<24, 128, 0, stream>>>(E, afw, cfw, out);
}

// Round 2
// 275.425 us; speedup vs baseline: 1.1882x; 1.1882x over previous
//
#include <hip/hip_runtime.h>
#include <math.h>

// ---------------- constants ----------------
// N=100 nodes, IN_C=65536, OUT_C=60, K=3 cheb, 2 heads, 1600 edges
#define KDIM    65536
#define NNODES  100
#define OUTC    60
#define KC      128         // K-chunks of 512
#define CHUNK   512
#define YW      64          // padded col width of Y
#define YSLAB   (NNODES*YW) // 6400 floats per hk

// ws layout (float offsets)
#define WS_S    0           // 10000
#define WS_Y    10048       // 6*6400 = 38400
#define WS_E    48448       // 2*6000 = 12000

typedef short bf16x8 __attribute__((ext_vector_type(8)));
typedef float f32x4  __attribute__((ext_vector_type(4)));

__device__ inline short f2bf(float f) {
    union { float f; unsigned u; } x; x.f = f;
    unsigned r = x.u + 0x7FFFu + ((x.u >> 16) & 1u);   // RNE (finite inputs)
    return (short)(r >> 16);
}

// ---------------- kernel 1: build dense S = -D^-1/2 A D^-1/2 ; zero Y ----------
__global__ __launch_bounds__(256) void k_build_s(const int* __restrict__ ei,
                                                 float* __restrict__ S,
                                                 float* __restrict__ Y) {
    __shared__ int   deg[NNODES];
    __shared__ float dinv[NNODES];
    const int t = threadIdx.x;
    if (t < NNODES) deg[t] = 0;
    for (int i = t; i < NNODES * NNODES; i += 256) S[i] = 0.f;
    for (int i = t; i < 6 * YSLAB; i += 256) Y[i] = 0.f;
    __syncthreads();
    const int* src = ei;
    const int* dst = ei + 1600;
    for (int e = t; e < 1600; e += 256) atomicAdd(&deg[src[e]], 1);
    __syncthreads();
    if (t < NNODES) { int d = deg[t]; dinv[t] = (d > 0) ? rsqrtf((float)d) : 0.f; }
    __syncthreads();
    for (int e = t; e < 1600; e += 256) {
        int s = src[e], d = dst[e];
        atomicAdd(&S[d * NNODES + s], -dinv[s] * dinv[d]);
    }
}

// ---------------- kernel 2: bf16 MFMA GEMM, atomic split-K into Y --------------
// grid (6, 128): x = hk (head*3+k), y = K-chunk of 512.
// block 512 = 8 waves: wave = (ntile 0..3) x (m-half 0..1).
__global__ __launch_bounds__(512, 6) void k_gemm(const float* __restrict__ x,
                                                 const float* __restrict__ wa,
                                                 const float* __restrict__ wc,
                                                 float* __restrict__ Y) {
    const int hk   = blockIdx.x;
    const int kc   = blockIdx.y;
    const int wave = threadIdx.x >> 6;
    const int lane = threadIdx.x & 63;
    const int nt   = wave & 3;          // n-tile (16 cols)
    const int mh   = wave >> 2;         // m-half: 0 -> tiles 0..3, 1 -> tiles 4..6
    const int n16  = lane & 15;
    const int quad = lane >> 4;
    const int NT   = mh ? 3 : 4;

    const float* W = (hk < 3 ? wa : wc) + (size_t)(hk % 3) * ((size_t)KDIM * OUTC);
    const int c0   = nt * 16;
    const int cidx = min(c0 + n16, OUTC - 1);     // clamp: cols 60..63 are junk

    int rowoff[4];
#pragma unroll
    for (int t = 0; t < 4; ++t)
        rowoff[t] = min(n16 + 16 * (mh * 4 + t), NNODES - 1) * KDIM;

    f32x4 acc[4] = {};
    const int kb0 = kc * CHUNK + quad * 8;

#pragma unroll 2
    for (int s = 0; s < CHUNK / 32; ++s) {
        const int kb = kb0 + s * 32;              // this lane's k-base (incl quad*8)
        // B fragment: W[kb+j][cidx], j=0..7 (stride 60 floats -> folded imm offsets)
        const float* bp = W + (size_t)kb * OUTC + cidx;
        bf16x8 bfr;
#pragma unroll
        for (int j = 0; j < 8; ++j) bfr[j] = f2bf(bp[j * OUTC]);
        // A fragments: x[row][kb .. kb+8), contiguous 32B per lane
#pragma unroll
        for (int t = 0; t < 4; ++t) {
            if (t < NT) {
                const float* ap = x + rowoff[t] + kb;
                float4 lo = *(const float4*)ap;
                float4 hi = *(const float4*)(ap + 4);
                bf16x8 afr;
                afr[0] = f2bf(lo.x); afr[1] = f2bf(lo.y);
                afr[2] = f2bf(lo.z); afr[3] = f2bf(lo.w);
                afr[4] = f2bf(hi.x); afr[5] = f2bf(hi.y);
                afr[6] = f2bf(hi.z); afr[7] = f2bf(hi.w);
                acc[t] = __builtin_amdgcn_mfma_f32_16x16x32_bf16(afr, bfr, acc[t], 0, 0, 0);
            }
        }
    }
    // D layout: col = lane&15, row = quad*4 + r within 16x16 tile
    float* Yb = Y + hk * YSLAB;
#pragma unroll
    for (int t = 0; t < 4; ++t) {
        if (t < NT) {
#pragma unroll
            for (int r = 0; r < 4; ++r) {
                int row = (mh * 4 + t) * 16 + quad * 4 + r;
                if (row < NNODES)
                    atomicAdd(&Yb[row * YW + c0 + n16], acc[t][r]);
            }
        }
    }
}

// ---------------- kernel 3: emb = tanh(Y0 + S Y1 + 2 S(S Y2) - Y2 + b) + vnr ----
// grid 120 = (head 2) x (col 60). 128 threads, thread n handles node n.
__global__ __launch_bounds__(128) void k_emb(const float* __restrict__ S,
                                             const float* __restrict__ Y,
                                             const float* __restrict__ vnr,
                                             const float* __restrict__ avw,
                                             const float* __restrict__ avb,
                                             const float* __restrict__ cvw,
                                             const float* __restrict__ cvb,
                                             const float* __restrict__ acb,
                                             const float* __restrict__ ccb,
                                             const float* __restrict__ afcb,
                                             const float* __restrict__ cfcb,
                                             float* __restrict__ E,
                                             float* __restrict__ out) {
    __shared__ float Sp[NNODES * 101];    // +1 pad: conflict-free row reads
    __shared__ float y0[NNODES], y1[NNODES], y2[NNODES], t2[NNODES];
    const int b = blockIdx.x, head = b / OUTC, c = b % OUTC;
    const int t = threadIdx.x;

    for (int i = t; i < NNODES * NNODES; i += 128)
        Sp[(i / NNODES) * 101 + (i % NNODES)] = S[i];
    const float* Yh = Y + (size_t)head * 3 * YSLAB;
    if (t < NNODES) {
        y0[t] = Yh[t * YW + c];
        y1[t] = Yh[YSLAB + t * YW + c];
        y2[t] = Yh[2 * YSLAB + t * YW + c];
    }
    if (b == 0 && t < 101) out[t] = (t < 100) ? afcb[t] : cfcb[0];  // seed with biases
    __syncthreads();

    float z1 = 0.f, s2 = 0.f;
    if (t < NNODES) {
        const float* sr = Sp + t * 101;
        for (int m = 0; m < NNODES; ++m) { z1 += sr[m] * y1[m]; s2 += sr[m] * y2[m]; }
        t2[t] = s2;
    }
    __syncthreads();
    if (t < NNODES) {
        const float* sr = Sp + t * 101;
        float t3 = 0.f;
        for (int m = 0; m < NNODES; ++m) t3 += sr[m] * t2[m];
        const float* cb = head ? ccb : acb;
        const float* vw = head ? cvw : avw;
        const float* vb = head ? cvb : avb;
        float u  = y0[t] + z1 + 2.f * t3 - y2[t] + cb[c];
        float vs = vnr[0] * vw[c]        + vb[c]
                 + vnr[1] * vw[OUTC + c] + vb[OUTC + c]
                 + vnr[2] * vw[2*OUTC+c] + vb[2*OUTC+c];
        E[head * (NNODES * OUTC) + t * OUTC + c] = tanhf(u) + vs;
    }
}

// ---------------- kernel 4: heads: logits += flat_a @ afw ; value += flat_c @ cfw
// grid 24 blocks x 250 flat indices each; d_out pre-seeded with biases by k_emb.
__global__ __launch_bounds__(128) void k_heads(const float* __restrict__ E,
                                               const float* __restrict__ afw,
                                               const float* __restrict__ cfw,
                                               float* __restrict__ out) {
    __shared__ float ea[250], ec[250];
    const int b = blockIdx.x, t = threadIdx.x;
    const int f0 = b * 250;
    for (int i = t; i < 250; i += 128) {
        ea[i] = E[f0 + i];
        ec[i] = E[NNODES * OUTC + f0 + i];
    }
    __syncthreads();
    if (t < 100) {
        float s = 0.f;
        for (int i = 0; i < 250; ++i) s += ea[i] * afw[(size_t)(f0 + i) * 100 + t];
        atomicAdd(&out[t], s);
    } else {
        float s = 0.f;
        for (int i = t - 100; i < 250; i += 28) s += ec[i] * cfw[f0 + i];
        atomicAdd(&out[100], s);
    }
}

// ---------------- launch ----------------
extern "C" void kernel_launch(void* const* d_in, const int* in_sizes, int n_in,
                              void* d_out, int out_size, void* d_ws, size_t ws_size,
                              hipStream_t stream) {
    const float* x    = (const float*)d_in[0];
    const int*   ei   = (const int*)  d_in[1];
    const float* vnr  = (const float*)d_in[2];
    const float* wa   = (const float*)d_in[3];
    const float* acb  = (const float*)d_in[4];
    const float* wc   = (const float*)d_in[5];
    const float* ccb  = (const float*)d_in[6];
    const float* avw  = (const float*)d_in[7];
    const float* avb  = (const float*)d_in[8];
    const float* cvw  = (const float*)d_in[9];
    const float* cvb  = (const float*)d_in[10];
    const float* afw  = (const float*)d_in[11];
    const float* afcb = (const float*)d_in[12];
    const float* cfw  = (const float*)d_in[13];
    const float* cfcb = (const float*)d_in[14];

    float* ws = (float*)d_ws;
    float* S  = ws + WS_S;
    float* Y  = ws + WS_Y;
    float* E  = ws + WS_E;
    float* out = (float*)d_out;

    k_build_s<<<1, 256, 0, stream>>>(ei, S, Y);
    k_gemm<<<dim3(6, KC), 512, 0, stream>>>(x, wa, wc, Y);
    k_emb<<<120, 128, 0, stream>>>(S, Y, vnr, avw, avb, cvw, cvb,
                                   acb, ccb, afcb, cfcb, E, out);
    k_heads<<<24, 128, 0, stream>>>(E, afw, cfw, out);
}

// Round 3
// 271.843 us; speedup vs baseline: 1.2039x; 1.0132x over previous
//
#include <hip/hip_runtime.h>
#include <math.h>

// ---------------- constants ----------------
// N=100 nodes, IN_C=65536, OUT_C=60, K=3 cheb, 2 heads, 1600 edges
#define KDIM    65536
#define NNODES  100
#define OUTC    60
#define CHUNK   256         // k-chunk per block
#define NKC     256         // KDIM / CHUNK
#define STEPS   (CHUNK/32)  // 8 MFMA k-steps per chunk
#define YW      64          // padded col width of Y
#define YSLAB   (NNODES*YW) // 6400 floats per hk

// ws layout (float offsets)
#define WS_S    0           // 10000
#define WS_Y    10048       // 6*6400 = 38400
#define WS_E    48448       // 2*6000 = 12000  (zero region ends at WS_E)

typedef short bf16x8 __attribute__((ext_vector_type(8)));
typedef float f32x4  __attribute__((ext_vector_type(4)));

__device__ inline short f2bf(float f) {
    union { float f; unsigned u; } x; x.f = f;
    unsigned r = x.u + 0x7FFFu + ((x.u >> 16) & 1u);   // RNE (finite inputs)
    return (short)(r >> 16);
}

// ---------------- kernel 1: scatter S = -D^-1/2 A D^-1/2 (S pre-zeroed) --------
__global__ __launch_bounds__(256) void k_build_s(const int* __restrict__ ei,
                                                 float* __restrict__ S) {
    __shared__ int   deg[NNODES];
    __shared__ float dinv[NNODES];
    const int t = threadIdx.x;
    if (t < NNODES) deg[t] = 0;
    __syncthreads();
    const int* src = ei;
    const int* dst = ei + 1600;
    for (int e = t; e < 1600; e += 256) atomicAdd(&deg[src[e]], 1);
    __syncthreads();
    if (t < NNODES) { int d = deg[t]; dinv[t] = (d > 0) ? rsqrtf((float)d) : 0.f; }
    __syncthreads();
    for (int e = t; e < 1600; e += 256) {
        int s = src[e], d = dst[e];
        atomicAdd(&S[d * NNODES + s], -dinv[s] * dinv[d]);
    }
}

// ---------------- kernel 2: bf16 MFMA GEMM, depth-2 register pipeline ----------
// grid (6, NKC): x = hk (head*3+k), y = k-chunk of 256.
// block 256 = 4 waves; wave = n-tile (16 cols); 7 m-tiles per wave.
__global__ __launch_bounds__(256, 2) void k_gemm(const float* __restrict__ x,
                                                 const float* __restrict__ wa,
                                                 const float* __restrict__ wc,
                                                 float* __restrict__ Y) {
    const int hk   = blockIdx.x;
    const int kc   = blockIdx.y;
    const int wave = threadIdx.x >> 6;
    const int lane = threadIdx.x & 63;
    const int n16  = lane & 15;
    const int quad = lane >> 4;

    const float* W = (hk < 3 ? wa : wc) + (size_t)(hk % 3) * ((size_t)KDIM * OUTC);
    const int c0   = wave * 16;
    const int cidx = min(c0 + n16, OUTC - 1);     // clamp: cols 60..63 are junk

    const int kb0 = kc * CHUNK + quad * 8;
    const float* ap[7];
#pragma unroll
    for (int t = 0; t < 7; ++t)
        ap[t] = x + (size_t)min(n16 + 16 * t, NNODES - 1) * KDIM + kb0;
    const float* bp = W + (size_t)kb0 * OUTC + cidx;

    float4 a[2][7][2];          // raw f32 double buffer (A)
    float  b[2][8];             // raw f32 double buffer (B)
    f32x4  acc[7] = {};

    auto LOAD = [&](int buf, int s) {
#pragma unroll
        for (int t = 0; t < 7; ++t) {
            const float* p = ap[t] + s * 32;
            a[buf][t][0] = *(const float4*)p;
            a[buf][t][1] = *(const float4*)(p + 4);
        }
        const float* q = bp + (size_t)s * 32 * OUTC;
#pragma unroll
        for (int j = 0; j < 8; ++j) b[buf][j] = q[j * OUTC];
    };

    auto CONSUME = [&](int buf) {
        bf16x8 bfr;
#pragma unroll
        for (int j = 0; j < 8; ++j) bfr[j] = f2bf(b[buf][j]);
#pragma unroll
        for (int t = 0; t < 7; ++t) {
            float4 lo = a[buf][t][0], hi = a[buf][t][1];
            bf16x8 afr;
            afr[0] = f2bf(lo.x); afr[1] = f2bf(lo.y);
            afr[2] = f2bf(lo.z); afr[3] = f2bf(lo.w);
            afr[4] = f2bf(hi.x); afr[5] = f2bf(hi.y);
            afr[6] = f2bf(hi.z); afr[7] = f2bf(hi.w);
            acc[t] = __builtin_amdgcn_mfma_f32_16x16x32_bf16(afr, bfr, acc[t], 0, 0, 0);
        }
    };

    LOAD(0, 0);
#pragma unroll
    for (int s = 0; s < STEPS; ++s) {
        if (s + 1 < STEPS) LOAD((s + 1) & 1, s + 1);   // issue next step's 16 loads
        CONSUME(s & 1);                                 // convert + 7 MFMA
    }

    // D layout: col = lane&15, row = quad*4 + r within 16x16 tile
    float* Yb = Y + hk * YSLAB;
#pragma unroll
    for (int t = 0; t < 7; ++t)
#pragma unroll
        for (int r = 0; r < 4; ++r) {
            int row = t * 16 + quad * 4 + r;
            if (row < NNODES)
                atomicAdd(&Yb[row * YW + c0 + n16], acc[t][r]);
        }
}

// ---------------- kernel 3: emb = tanh(Y0 + S Y1 + 2 S(S Y2) - Y2 + b) + vnr ----
// grid 120 = (head 2) x (col 60). 128 threads, thread n handles node n.
__global__ __launch_bounds__(128) void k_emb(const float* __restrict__ S,
                                             const float* __restrict__ Y,
                                             const float* __restrict__ vnr,
                                             const float* __restrict__ avw,
                                             const float* __restrict__ avb,
                                             const float* __restrict__ cvw,
                                             const float* __restrict__ cvb,
                                             const float* __restrict__ acb,
                                             const float* __restrict__ ccb,
                                             const float* __restrict__ afcb,
                                             const float* __restrict__ cfcb,
                                             float* __restrict__ E,
                                             float* __restrict__ out) {
    __shared__ float Sp[NNODES * 101];    // +1 pad: conflict-free row reads
    __shared__ float y0[NNODES], y1[NNODES], y2[NNODES], t2[NNODES];
    const int b = blockIdx.x, head = b / OUTC, c = b % OUTC;
    const int t = threadIdx.x;

    for (int i = t; i < NNODES * NNODES; i += 128)
        Sp[(i / NNODES) * 101 + (i % NNODES)] = S[i];
    const float* Yh = Y + (size_t)head * 3 * YSLAB;
    if (t < NNODES) {
        y0[t] = Yh[t * YW + c];
        y1[t] = Yh[YSLAB + t * YW + c];
        y2[t] = Yh[2 * YSLAB + t * YW + c];
    }
    if (b == 0 && t < 101) out[t] = (t < 100) ? afcb[t] : cfcb[0];  // seed with biases
    __syncthreads();

    float z1 = 0.f, s2 = 0.f;
    if (t < NNODES) {
        const float* sr = Sp + t * 101;
        for (int m = 0; m < NNODES; ++m) { z1 += sr[m] * y1[m]; s2 += sr[m] * y2[m]; }
        t2[t] = s2;
    }
    __syncthreads();
    if (t < NNODES) {
        const float* sr = Sp + t * 101;
        float t3 = 0.f;
        for (int m = 0; m < NNODES; ++m) t3 += sr[m] * t2[m];
        const float* cb = head ? ccb : acb;
        const float* vw = head ? cvw : avw;
        const float* vb = head ? cvb : avb;
        float u  = y0[t] + z1 + 2.f * t3 - y2[t] + cb[c];
        float vs = vnr[0] * vw[c]        + vb[c]
                 + vnr[1] * vw[OUTC + c] + vb[OUTC + c]
                 + vnr[2] * vw[2*OUTC+c] + vb[2*OUTC+c];
        E[head * (NNODES * OUTC) + t * OUTC + c] = tanhf(u) + vs;
    }
}

// ---------------- kernel 4: heads: logits += flat_a @ afw ; value += flat_c @ cfw
// grid 24 blocks x 250 flat indices each; d_out pre-seeded with biases by k_emb.
__global__ __launch_bounds__(128) void k_heads(const float* __restrict__ E,
                                               const float* __restrict__ afw,
                                               const float* __restrict__ cfw,
                                               float* __restrict__ out) {
    __shared__ float ea[250], ec[250];
    const int b = blockIdx.x, t = threadIdx.x;
    const int f0 = b * 250;
    for (int i = t; i < 250; i += 128) {
        ea[i] = E[f0 + i];
        ec[i] = E[NNODES * OUTC + f0 + i];
    }
    __syncthreads();
    if (t < 100) {
        float s = 0.f;
        for (int i = 0; i < 250; ++i) s += ea[i] * afw[(size_t)(f0 + i) * 100 + t];
        atomicAdd(&out[t], s);
    } else {
        float s = 0.f;
        for (int i = t - 100; i < 250; i += 28) s += ec[i] * cfw[f0 + i];
        atomicAdd(&out[100], s);
    }
}

// ---------------- launch ----------------
extern "C" void kernel_launch(void* const* d_in, const int* in_sizes, int n_in,
                              void* d_out, int out_size, void* d_ws, size_t ws_size,
                              hipStream_t stream) {
    const float* x    = (const float*)d_in[0];
    const int*   ei   = (const int*)  d_in[1];
    const float* vnr  = (const float*)d_in[2];
    const float* wa   = (const float*)d_in[3];
    const float* acb  = (const float*)d_in[4];
    const float* wc   = (const float*)d_in[5];
    const float* ccb  = (const float*)d_in[6];
    const float* avw  = (const float*)d_in[7];
    const float* avb  = (const float*)d_in[8];
    const float* cvw  = (const float*)d_in[9];
    const float* cvb  = (const float*)d_in[10];
    const float* afw  = (const float*)d_in[11];
    const float* afcb = (const float*)d_in[12];
    const float* cfw  = (const float*)d_in[13];
    const float* cfcb = (const float*)d_in[14];

    float* ws = (float*)d_ws;
    float* S  = ws + WS_S;
    float* Y  = ws + WS_Y;
    float* E  = ws + WS_E;
    float* out = (float*)d_out;

    hipMemsetAsync(ws, 0, (size_t)WS_E * sizeof(float), stream);  // zero S + Y
    k_build_s<<<1, 256, 0, stream>>>(ei, S);
    k_gemm<<<dim3(6, NKC), 256, 0, stream>>>(x, wa, wc, Y);
    k_emb<<<120, 128, 0, stream>>>(S, Y, vnr, avw, avb, cvw, cvb,
                                   acb, ccb, afcb, cfcb, E, out);
    k_heads<<<24, 128, 0, stream>>>(E, afw, cfw, out);
}

// Round 4
// 270.933 us; speedup vs baseline: 1.2079x; 1.0034x over previous
//
#include <hip/hip_runtime.h>
#include <math.h>

// ---------------- constants ----------------
// N=100 nodes, IN_C=65536, OUT_C=60, K=3 cheb, 2 heads, 1600 edges
#define KDIM    65536
#define NNODES  100
#define OUTC    60
#define YW      64          // padded col width of Y
#define YSLAB   (NNODES*YW) // 6400 floats per hk

// f32 fallback GEMM chunking
#define CHUNK   256
#define NKC     256
#define STEPS   (CHUNK/32)
// bf16 fast-path GEMM chunking
#define CHUNK2  512
#define NKC2    (KDIM/CHUNK2)   // 128

// ws layout (float offsets for the f32 part)
#define WS_S    0           // 10000 floats
#define WS_Y    10048       // 6*6400 = 38400 floats
#define WS_E    48448       // 2*6000 = 12000 floats (zero region ends here)
// bf16 scratch (byte offsets)
#define XB_OFF_BYTES   245760ull                      // float offset 61440
#define XB_BYTES       (100ull*65536ull*2ull)         // 13107200
#define WT_OFF_BYTES   (XB_OFF_BYTES + XB_BYTES)      // 13352960
#define WT_BYTES       (6ull*60ull*65536ull*2ull)     // 47185920
#define WS_NEED_BYTES  (WT_OFF_BYTES + WT_BYTES)      // 60538880

typedef short bf16x8 __attribute__((ext_vector_type(8)));
typedef float f32x4  __attribute__((ext_vector_type(4)));
typedef unsigned short ushort8 __attribute__((ext_vector_type(8)));

__device__ inline unsigned short f2bf(float f) {
    union { float f; unsigned u; } x; x.f = f;
    unsigned r = x.u + 0x7FFFu + ((x.u >> 16) & 1u);   // RNE (finite inputs)
    return (unsigned short)(r >> 16);
}

// ---------------- kernel 1: scatter S = -D^-1/2 A D^-1/2 (S pre-zeroed) --------
__global__ __launch_bounds__(256) void k_build_s(const int* __restrict__ ei,
                                                 float* __restrict__ S) {
    __shared__ int   deg[NNODES];
    __shared__ float dinv[NNODES];
    const int t = threadIdx.x;
    if (t < NNODES) deg[t] = 0;
    __syncthreads();
    const int* src = ei;
    const int* dst = ei + 1600;
    for (int e = t; e < 1600; e += 256) atomicAdd(&deg[src[e]], 1);
    __syncthreads();
    if (t < NNODES) { int d = deg[t]; dinv[t] = (d > 0) ? rsqrtf((float)d) : 0.f; }
    __syncthreads();
    for (int e = t; e < 1600; e += 256) {
        int s = src[e], d = dst[e];
        atomicAdd(&S[d * NNODES + s], -dinv[s] * dinv[d]);
    }
}

// ---------------- pass 1a: x f32 -> bf16 (pure stream) -------------------------
// 6,553,600 elems in groups of 8: 819200 groups. 800 blocks x 256 thr x 4 iters.
__global__ __launch_bounds__(256) void k_cvt_x(const float* __restrict__ x,
                                               ushort8* __restrict__ xb) {
    int g = blockIdx.x * 256 + threadIdx.x;
    for (int i = g; i < 819200; i += 204800) {
        const float4 lo = ((const float4*)x)[2 * i];
        const float4 hi = ((const float4*)x)[2 * i + 1];
        ushort8 o;
        o[0] = f2bf(lo.x); o[1] = f2bf(lo.y); o[2] = f2bf(lo.z); o[3] = f2bf(lo.w);
        o[4] = f2bf(hi.x); o[5] = f2bf(hi.y); o[6] = f2bf(hi.z); o[7] = f2bf(hi.w);
        xb[i] = o;
    }
}

// ---------------- pass 1b: W [K][60] f32 -> W^T [60][K] bf16, LDS transpose ----
// grid (1024, 6): 64-k x 60-c tile per block. Tile is 64 full rows = contiguous.
__global__ __launch_bounds__(256) void k_cvt_w(const float* __restrict__ wa,
                                               const float* __restrict__ wc,
                                               unsigned* __restrict__ wt) {
    __shared__ unsigned short tile[64 * 61];
    const int kb = blockIdx.x, hk = blockIdx.y, t = threadIdx.x;
    const float* W = (hk < 3 ? wa : wc)
                   + (size_t)(hk % 3) * ((size_t)KDIM * OUTC)
                   + (size_t)kb * 3840;
    // read: 960 float4 = 3840 contiguous floats, convert, scatter to padded tile
#pragma unroll
    for (int it = 0; it < 4; ++it) {
        int i4 = t + it * 256;
        if (i4 < 960) {
            float4 v = ((const float4*)W)[i4];
            int i = i4 * 4;
            tile[(i / 60) * 61 + (i % 60)]             = f2bf(v.x);
            tile[((i+1) / 60) * 61 + ((i+1) % 60)]     = f2bf(v.y);
            tile[((i+2) / 60) * 61 + ((i+2) % 60)]     = f2bf(v.z);
            tile[((i+3) / 60) * 61 + ((i+3) % 60)]     = f2bf(v.w);
        }
    }
    __syncthreads();
    // write: 1920 dwords (c = d>>5, k-pair = d&31), coalesced in k
#pragma unroll
    for (int it = 0; it < 8; ++it) {
        int d = t + it * 256;
        if (d < 1920) {
            int c = d >> 5, jp = d & 31;
            unsigned lo = tile[(2 * jp)     * 61 + c];
            unsigned hi = tile[(2 * jp + 1) * 61 + c];
            size_t elem = (size_t)(hk * 60 + c) * KDIM + (size_t)kb * 64 + 2 * jp;
            wt[elem >> 1] = lo | (hi << 16);
        }
    }
}

// ---------------- pass 2: bf16 MFMA GEMM, k-contiguous A and B -----------------
// grid (6, 128): hk x k-chunk of 512. block 256 = 4 waves (n-tiles), 7 m-tiles.
// Per step: 8 x 16B loads + 7 MFMA, ~zero VALU.
__global__ __launch_bounds__(256) void k_gemm2(const unsigned short* __restrict__ xb,
                                               const unsigned short* __restrict__ wt,
                                               float* __restrict__ Y) {
    const int hk   = blockIdx.x;
    const int kc   = blockIdx.y;
    const int wave = threadIdx.x >> 6;
    const int lane = threadIdx.x & 63;
    const int n16  = lane & 15;
    const int quad = lane >> 4;
    const int c0   = wave * 16;
    const int cidx = min(c0 + n16, OUTC - 1);   // cols 60..63 are junk (clamped)

    const int kb0 = kc * CHUNK2 + quad * 8;
    const unsigned short* ap[7];
#pragma unroll
    for (int t = 0; t < 7; ++t)
        ap[t] = xb + (size_t)min(n16 + 16 * t, NNODES - 1) * KDIM + kb0;
    const unsigned short* bp = wt + (size_t)(hk * 60 + cidx) * KDIM + kb0;

    f32x4 acc[7] = {};
#pragma unroll 4
    for (int s = 0; s < CHUNK2 / 32; ++s) {
        bf16x8 bfr = *(const bf16x8*)(bp + s * 32);
#pragma unroll
        for (int t = 0; t < 7; ++t) {
            bf16x8 afr = *(const bf16x8*)(ap[t] + s * 32);
            acc[t] = __builtin_amdgcn_mfma_f32_16x16x32_bf16(afr, bfr, acc[t], 0, 0, 0);
        }
    }
    // D layout: col = lane&15, row = quad*4 + r within 16x16 tile
    float* Yb = Y + hk * YSLAB;
#pragma unroll
    for (int t = 0; t < 7; ++t)
#pragma unroll
        for (int r = 0; r < 4; ++r) {
            int row = t * 16 + quad * 4 + r;
            if (row < NNODES)
                atomicAdd(&Yb[row * YW + c0 + n16], acc[t][r]);
        }
}

// ---------------- fallback f32 GEMM (used only if ws is too small) -------------
__global__ __launch_bounds__(256, 2) void k_gemm_f32(const float* __restrict__ x,
                                                     const float* __restrict__ wa,
                                                     const float* __restrict__ wc,
                                                     float* __restrict__ Y) {
    const int hk   = blockIdx.x;
    const int kc   = blockIdx.y;
    const int wave = threadIdx.x >> 6;
    const int lane = threadIdx.x & 63;
    const int n16  = lane & 15;
    const int quad = lane >> 4;
    const float* W = (hk < 3 ? wa : wc) + (size_t)(hk % 3) * ((size_t)KDIM * OUTC);
    const int c0   = wave * 16;
    const int cidx = min(c0 + n16, OUTC - 1);
    const int kb0  = kc * CHUNK + quad * 8;
    const float* ap[7];
#pragma unroll
    for (int t = 0; t < 7; ++t)
        ap[t] = x + (size_t)min(n16 + 16 * t, NNODES - 1) * KDIM + kb0;
    const float* bp = W + (size_t)kb0 * OUTC + cidx;
    f32x4 acc[7] = {};
#pragma unroll 2
    for (int s = 0; s < STEPS; ++s) {
        bf16x8 bfr;
        const float* q = bp + (size_t)s * 32 * OUTC;
#pragma unroll
        for (int j = 0; j < 8; ++j) bfr[j] = (short)f2bf(q[j * OUTC]);
#pragma unroll
        for (int t = 0; t < 7; ++t) {
            const float* p = ap[t] + s * 32;
            float4 lo = *(const float4*)p;
            float4 hi = *(const float4*)(p + 4);
            bf16x8 afr;
            afr[0] = (short)f2bf(lo.x); afr[1] = (short)f2bf(lo.y);
            afr[2] = (short)f2bf(lo.z); afr[3] = (short)f2bf(lo.w);
            afr[4] = (short)f2bf(hi.x); afr[5] = (short)f2bf(hi.y);
            afr[6] = (short)f2bf(hi.z); afr[7] = (short)f2bf(hi.w);
            acc[t] = __builtin_amdgcn_mfma_f32_16x16x32_bf16(afr, bfr, acc[t], 0, 0, 0);
        }
    }
    float* Yb = Y + hk * YSLAB;
#pragma unroll
    for (int t = 0; t < 7; ++t)
#pragma unroll
        for (int r = 0; r < 4; ++r) {
            int row = t * 16 + quad * 4 + r;
            if (row < NNODES)
                atomicAdd(&Yb[row * YW + c0 + n16], acc[t][r]);
        }
}

// ---------------- kernel 3: emb = tanh(Y0 + S Y1 + 2 S(S Y2) - Y2 + b) + vnr ----
__global__ __launch_bounds__(128) void k_emb(const float* __restrict__ S,
                                             const float* __restrict__ Y,
                                             const float* __restrict__ vnr,
                                             const float* __restrict__ avw,
                                             const float* __restrict__ avb,
                                             const float* __restrict__ cvw,
                                             const float* __restrict__ cvb,
                                             const float* __restrict__ acb,
                                             const float* __restrict__ ccb,
                                             const float* __restrict__ afcb,
                                             const float* __restrict__ cfcb,
                                             float* __restrict__ E,
                                             float* __restrict__ out) {
    __shared__ float Sp[NNODES * 101];
    __shared__ float y0[NNODES], y1[NNODES], y2[NNODES], t2[NNODES];
    const int b = blockIdx.x, head = b / OUTC, c = b % OUTC;
    const int t = threadIdx.x;

    for (int i = t; i < NNODES * NNODES; i += 128)
        Sp[(i / NNODES) * 101 + (i % NNODES)] = S[i];
    const float* Yh = Y + (size_t)head * 3 * YSLAB;
    if (t < NNODES) {
        y0[t] = Yh[t * YW + c];
        y1[t] = Yh[YSLAB + t * YW + c];
        y2[t] = Yh[2 * YSLAB + t * YW + c];
    }
    if (b == 0 && t < 101) out[t] = (t < 100) ? afcb[t] : cfcb[0];
    __syncthreads();

    float z1 = 0.f, s2 = 0.f;
    if (t < NNODES) {
        const float* sr = Sp + t * 101;
        for (int m = 0; m < NNODES; ++m) { z1 += sr[m] * y1[m]; s2 += sr[m] * y2[m]; }
        t2[t] = s2;
    }
    __syncthreads();
    if (t < NNODES) {
        const float* sr = Sp + t * 101;
        float t3 = 0.f;
        for (int m = 0; m < NNODES; ++m) t3 += sr[m] * t2[m];
        const float* cb = head ? ccb : acb;
        const float* vw = head ? cvw : avw;
        const float* vb = head ? cvb : avb;
        float u  = y0[t] + z1 + 2.f * t3 - y2[t] + cb[c];
        float vs = vnr[0] * vw[c]        + vb[c]
                 + vnr[1] * vw[OUTC + c] + vb[OUTC + c]
                 + vnr[2] * vw[2*OUTC+c] + vb[2*OUTC+c];
        E[head * (NNODES * OUTC) + t * OUTC + c] = tanhf(u) + vs;
    }
}

// ---------------- kernel 4: heads ----------------------------------------------
__global__ __launch_bounds__(128) void k_heads(const float* __restrict__ E,
                                               const float* __restrict__ afw,
                                               const float* __restrict__ cfw,
                                               float* __restrict__ out) {
    __shared__ float ea[250], ec[250];
    const int b = blockIdx.x, t = threadIdx.x;
    const int f0 = b * 250;
    for (int i = t; i < 250; i += 128) {
        ea[i] = E[f0 + i];
        ec[i] = E[NNODES * OUTC + f0 + i];
    }
    __syncthreads();
    if (t < 100) {
        float s = 0.f;
        for (int i = 0; i < 250; ++i) s += ea[i] * afw[(size_t)(f0 + i) * 100 + t];
        atomicAdd(&out[t], s);
    } else {
        float s = 0.f;
        for (int i = t - 100; i < 250; i += 28) s += ec[i] * cfw[f0 + i];
        atomicAdd(&out[100], s);
    }
}

// ---------------- launch ----------------
extern "C" void kernel_launch(void* const* d_in, const int* in_sizes, int n_in,
                              void* d_out, int out_size, void* d_ws, size_t ws_size,
                              hipStream_t stream) {
    const float* x    = (const float*)d_in[0];
    const int*   ei   = (const int*)  d_in[1];
    const float* vnr  = (const float*)d_in[2];
    const float* wa   = (const float*)d_in[3];
    const float* acb  = (const float*)d_in[4];
    const float* wc   = (const float*)d_in[5];
    const float* ccb  = (const float*)d_in[6];
    const float* avw  = (const float*)d_in[7];
    const float* avb  = (const float*)d_in[8];
    const float* cvw  = (const float*)d_in[9];
    const float* cvb  = (const float*)d_in[10];
    const float* afw  = (const float*)d_in[11];
    const float* afcb = (const float*)d_in[12];
    const float* cfw  = (const float*)d_in[13];
    const float* cfcb = (const float*)d_in[14];

    float* ws = (float*)d_ws;
    float* S  = ws + WS_S;
    float* Y  = ws + WS_Y;
    float* E  = ws + WS_E;
    float* out = (float*)d_out;

    hipMemsetAsync(ws, 0, (size_t)WS_E * sizeof(float), stream);  // zero S + Y
    k_build_s<<<1, 256, 0, stream>>>(ei, S);

    if (ws_size >= WS_NEED_BYTES) {
        unsigned short* xb = (unsigned short*)((char*)d_ws + XB_OFF_BYTES);
        unsigned*       wt = (unsigned*)((char*)d_ws + WT_OFF_BYTES);
        k_cvt_x<<<800, 256, 0, stream>>>(x, (ushort8*)xb);
        k_cvt_w<<<dim3(1024, 6), 256, 0, stream>>>(wa, wc, wt);
        k_gemm2<<<dim3(6, NKC2), 256, 0, stream>>>(xb, (const unsigned short*)wt, Y);
    } else {
        k_gemm_f32<<<dim3(6, NKC), 256, 0, stream>>>(x, wa, wc, Y);
    }

    k_emb<<<120, 128, 0, stream>>>(S, Y, vnr, avw, avb, cvw, cvb,
                                   acb, ccb, afcb, cfcb, E, out);
    k_heads<<<24, 128, 0, stream>>>(E, afw, cfw, out);
}

// Round 5
// 238.116 us; speedup vs baseline: 1.3744x; 1.1378x over previous
//
#include <hip/hip_runtime.h>
#include <math.h>

// ---------------- constants ----------------
// N=100 nodes, IN_C=65536, OUT_C=60, K=3 cheb, 2 heads, 1600 edges
#define KDIM    65536
#define NNODES  100
#define OUTC    60
#define YW      64          // padded col width of Y
#define YSLAB   (NNODES*YW) // 6400 floats per hk

// fused GEMM chunking
#define BK3     256
#define NKC3    (KDIM/BK3)  // 256
// f32 fallback GEMM chunking
#define CHUNK   256
#define NKC     256
#define STEPS   (CHUNK/32)

// ws layout (float offsets)
#define WS_S    0           // 10000 floats
#define WS_Y    10048       // 6*6400 = 38400 floats
#define WS_E    48448       // 2*6000 = 12000 floats (zero region ends here)
// bf16 x scratch (byte offsets)
#define XB_OFF_BYTES   245760ull                      // float offset 61440
#define XB_BYTES       (100ull*65536ull*2ull)         // 13107200
#define WS_NEED_BYTES  (XB_OFF_BYTES + XB_BYTES)

typedef short bf16x8 __attribute__((ext_vector_type(8)));
typedef float f32x4  __attribute__((ext_vector_type(4)));
typedef unsigned short ushort8 __attribute__((ext_vector_type(8)));

__device__ inline unsigned short f2bf(float f) {
    union { float f; unsigned u; } x; x.f = f;
    unsigned r = x.u + 0x7FFFu + ((x.u >> 16) & 1u);   // RNE (finite inputs)
    return (unsigned short)(r >> 16);
}

// ---------------- kernel 1: scatter S = -D^-1/2 A D^-1/2 (S pre-zeroed) --------
__global__ __launch_bounds__(256) void k_build_s(const int* __restrict__ ei,
                                                 float* __restrict__ S) {
    __shared__ int   deg[NNODES];
    __shared__ float dinv[NNODES];
    const int t = threadIdx.x;
    if (t < NNODES) deg[t] = 0;
    __syncthreads();
    const int* src = ei;
    const int* dst = ei + 1600;
    for (int e = t; e < 1600; e += 256) atomicAdd(&deg[src[e]], 1);
    __syncthreads();
    if (t < NNODES) { int d = deg[t]; dinv[t] = (d > 0) ? rsqrtf((float)d) : 0.f; }
    __syncthreads();
    for (int e = t; e < 1600; e += 256) {
        int s = src[e], d = dst[e];
        atomicAdd(&S[d * NNODES + s], -dinv[s] * dinv[d]);
    }
}

// ---------------- pass 1: x f32 -> bf16 (pure stream) --------------------------
__global__ __launch_bounds__(256) void k_cvt_x(const float* __restrict__ x,
                                               ushort8* __restrict__ xb) {
    int g = blockIdx.x * 256 + threadIdx.x;
    for (int i = g; i < 819200; i += 204800) {
        const float4 lo = ((const float4*)x)[2 * i];
        const float4 hi = ((const float4*)x)[2 * i + 1];
        ushort8 o;
        o[0] = f2bf(lo.x); o[1] = f2bf(lo.y); o[2] = f2bf(lo.z); o[3] = f2bf(lo.w);
        o[4] = f2bf(hi.x); o[5] = f2bf(hi.y); o[6] = f2bf(hi.z); o[7] = f2bf(hi.w);
        xb[i] = o;
    }
}

// ---------------- pass 2: fused transpose+convert+GEMM -------------------------
// grid (6, 256): hk x k-chunk of 256. block 512 = 8 waves:
//   wave = (n-tile 0..3) x (m-half 0..1). LDS: raw f32 W chunk [256][60] = 60 KB,
//   staged by global_load_lds dwordx4 (60 x 1KB insts), B-frags read strided from
//   LDS (quad-rotated issue order -> <=2-way bank conflicts) + f2bf in VALU.
//   A-frags: direct global bf16 16B loads (no LDS dep -> overlap with DMA).
__global__ __launch_bounds__(512, 4) void k_gemm3(const unsigned short* __restrict__ xb,
                                                  const float* __restrict__ wa,
                                                  const float* __restrict__ wc,
                                                  float* __restrict__ Y) {
    __shared__ float Wl[BK3 * OUTC];   // 15360 floats = 60 KB
    const int hk   = blockIdx.x;
    const int kc   = blockIdx.y;
    const int wave = threadIdx.x >> 6;
    const int lane = threadIdx.x & 63;
    const int nt   = wave & 3;
    const int mh   = wave >> 2;
    const int n16  = lane & 15;
    const int quad = lane >> 4;
    const int NT   = mh ? 3 : 4;
    const int c0   = nt * 16;
    const int cidx = min(c0 + n16, OUTC - 1);   // cols 60..63 junk (clamped)

    // ---- stage W chunk (61440 B) into LDS via async DMA ----
    const float* Wg = (hk < 3 ? wa : wc)
                    + (size_t)(hk % 3) * ((size_t)KDIM * OUTC)
                    + (size_t)kc * (BK3 * OUTC);
    for (int i = wave; i < 60; i += 8) {
        const float* gp = Wg + i * 256 + lane * 4;
        __builtin_amdgcn_global_load_lds(
            (const __attribute__((address_space(1))) void*)gp,
            (__attribute__((address_space(3))) void*)&Wl[i * 256], 16, 0, 0);
    }

    // ---- A pointers (independent of LDS; loads can overlap DMA) ----
    const unsigned short* ap[4];
#pragma unroll
    for (int t = 0; t < 4; ++t)
        ap[t] = xb + (size_t)min(n16 + 16 * (mh * 4 + t), NNODES - 1) * KDIM
                   + kc * BK3 + quad * 8;

    __syncthreads();   // waits vmcnt(0): DMA complete

    f32x4 acc[4] = {};
#pragma unroll
    for (int s = 0; s < BK3 / 32; ++s) {
        bf16x8 bfr;
#pragma unroll
        for (int j = 0; j < 8; ++j) {
            int jj = (j + quad * 2) & 7;   // rotate issue order: de-conflict quads
            bfr[jj] = (short)f2bf(Wl[(s * 32 + quad * 8 + jj) * OUTC + cidx]);
        }
#pragma unroll
        for (int t = 0; t < 4; ++t) {
            if (t < NT) {
                bf16x8 afr = *(const bf16x8*)(ap[t] + s * 32);
                acc[t] = __builtin_amdgcn_mfma_f32_16x16x32_bf16(afr, bfr, acc[t], 0, 0, 0);
            }
        }
    }

    // D layout: col = lane&15, row = quad*4 + r within 16x16 tile
    float* Yb = Y + hk * YSLAB;
#pragma unroll
    for (int t = 0; t < 4; ++t) {
        if (t < NT) {
#pragma unroll
            for (int r = 0; r < 4; ++r) {
                int row = (mh * 4 + t) * 16 + quad * 4 + r;
                if (row < NNODES)
                    atomicAdd(&Yb[row * YW + c0 + n16], acc[t][r]);
            }
        }
    }
}

// ---------------- fallback f32 GEMM (used only if ws is too small) -------------
__global__ __launch_bounds__(256, 2) void k_gemm_f32(const float* __restrict__ x,
                                                     const float* __restrict__ wa,
                                                     const float* __restrict__ wc,
                                                     float* __restrict__ Y) {
    const int hk   = blockIdx.x;
    const int kc   = blockIdx.y;
    const int wave = threadIdx.x >> 6;
    const int lane = threadIdx.x & 63;
    const int n16  = lane & 15;
    const int quad = lane >> 4;
    const float* W = (hk < 3 ? wa : wc) + (size_t)(hk % 3) * ((size_t)KDIM * OUTC);
    const int c0   = wave * 16;
    const int cidx = min(c0 + n16, OUTC - 1);
    const int kb0  = kc * CHUNK + quad * 8;
    const float* ap[7];
#pragma unroll
    for (int t = 0; t < 7; ++t)
        ap[t] = x + (size_t)min(n16 + 16 * t, NNODES - 1) * KDIM + kb0;
    const float* bp = W + (size_t)kb0 * OUTC + cidx;
    f32x4 acc[7] = {};
#pragma unroll 2
    for (int s = 0; s < STEPS; ++s) {
        bf16x8 bfr;
        const float* q = bp + (size_t)s * 32 * OUTC;
#pragma unroll
        for (int j = 0; j < 8; ++j) bfr[j] = (short)f2bf(q[j * OUTC]);
#pragma unroll
        for (int t = 0; t < 7; ++t) {
            const float* p = ap[t] + s * 32;
            float4 lo = *(const float4*)p;
            float4 hi = *(const float4*)(p + 4);
            bf16x8 afr;
            afr[0] = (short)f2bf(lo.x); afr[1] = (short)f2bf(lo.y);
            afr[2] = (short)f2bf(lo.z); afr[3] = (short)f2bf(lo.w);
            afr[4] = (short)f2bf(hi.x); afr[5] = (short)f2bf(hi.y);
            afr[6] = (short)f2bf(hi.z); afr[7] = (short)f2bf(hi.w);
            acc[t] = __builtin_amdgcn_mfma_f32_16x16x32_bf16(afr, bfr, acc[t], 0, 0, 0);
        }
    }
    float* Yb = Y + hk * YSLAB;
#pragma unroll
    for (int t = 0; t < 7; ++t)
#pragma unroll
        for (int r = 0; r < 4; ++r) {
            int row = t * 16 + quad * 4 + r;
            if (row < NNODES)
                atomicAdd(&Yb[row * YW + c0 + n16], acc[t][r]);
        }
}

// ---------------- kernel 3: emb = tanh(Y0 + S Y1 + 2 S(S Y2) - Y2 + b) + vnr ----
__global__ __launch_bounds__(128) void k_emb(const float* __restrict__ S,
                                             const float* __restrict__ Y,
                                             const float* __restrict__ vnr,
                                             const float* __restrict__ avw,
                                             const float* __restrict__ avb,
                                             const float* __restrict__ cvw,
                                             const float* __restrict__ cvb,
                                             const float* __restrict__ acb,
                                             const float* __restrict__ ccb,
                                             const float* __restrict__ afcb,
                                             const float* __restrict__ cfcb,
                                             float* __restrict__ E,
                                             float* __restrict__ out) {
    __shared__ float Sp[NNODES * 101];
    __shared__ float y0[NNODES], y1[NNODES], y2[NNODES], t2[NNODES];
    const int b = blockIdx.x, head = b / OUTC, c = b % OUTC;
    const int t = threadIdx.x;

    for (int i = t; i < NNODES * NNODES; i += 128)
        Sp[(i / NNODES) * 101 + (i % NNODES)] = S[i];
    const float* Yh = Y + (size_t)head * 3 * YSLAB;
    if (t < NNODES) {
        y0[t] = Yh[t * YW + c];
        y1[t] = Yh[YSLAB + t * YW + c];
        y2[t] = Yh[2 * YSLAB + t * YW + c];
    }
    if (b == 0 && t < 101) out[t] = (t < 100) ? afcb[t] : cfcb[0];
    __syncthreads();

    float z1 = 0.f, s2 = 0.f;
    if (t < NNODES) {
        const float* sr = Sp + t * 101;
        for (int m = 0; m < NNODES; ++m) { z1 += sr[m] * y1[m]; s2 += sr[m] * y2[m]; }
        t2[t] = s2;
    }
    __syncthreads();
    if (t < NNODES) {
        const float* sr = Sp + t * 101;
        float t3 = 0.f;
        for (int m = 0; m < NNODES; ++m) t3 += sr[m] * t2[m];
        const float* cb = head ? ccb : acb;
        const float* vw = head ? cvw : avw;
        const float* vb = head ? cvb : avb;
        float u  = y0[t] + z1 + 2.f * t3 - y2[t] + cb[c];
        float vs = vnr[0] * vw[c]        + vb[c]
                 + vnr[1] * vw[OUTC + c] + vb[OUTC + c]
                 + vnr[2] * vw[2*OUTC+c] + vb[2*OUTC+c];
        E[head * (NNODES * OUTC) + t * OUTC + c] = tanhf(u) + vs;
    }
}

// ---------------- kernel 4: heads — grid 240, 25 flat rows per block -----------
__global__ __launch_bounds__(128) void k_heads(const float* __restrict__ E,
                                               const float* __restrict__ afw,
                                               const float* __restrict__ cfw,
                                               float* __restrict__ out) {
    __shared__ float ea[25], ec[25];
    const int b = blockIdx.x, t = threadIdx.x;
    const int f0 = b * 25;
    if (t < 25) {
        ea[t] = E[f0 + t];
        ec[t] = E[NNODES * OUTC + f0 + t];
    }
    __syncthreads();
    if (t < 100) {
        float s = 0.f;
#pragma unroll
        for (int i = 0; i < 25; ++i) s += ea[i] * afw[(size_t)(f0 + i) * 100 + t];
        atomicAdd(&out[t], s);
    } else if (t == 100) {
        float s = 0.f;
#pragma unroll
        for (int i = 0; i < 25; ++i) s += ec[i] * cfw[f0 + i];
        atomicAdd(&out[100], s);
    }
}

// ---------------- launch ----------------
extern "C" void kernel_launch(void* const* d_in, const int* in_sizes, int n_in,
                              void* d_out, int out_size, void* d_ws, size_t ws_size,
                              hipStream_t stream) {
    const float* x    = (const float*)d_in[0];
    const int*   ei   = (const int*)  d_in[1];
    const float* vnr  = (const float*)d_in[2];
    const float* wa   = (const float*)d_in[3];
    const float* acb  = (const float*)d_in[4];
    const float* wc   = (const float*)d_in[5];
    const float* ccb  = (const float*)d_in[6];
    const float* avw  = (const float*)d_in[7];
    const float* avb  = (const float*)d_in[8];
    const float* cvw  = (const float*)d_in[9];
    const float* cvb  = (const float*)d_in[10];
    const float* afw  = (const float*)d_in[11];
    const float* afcb = (const float*)d_in[12];
    const float* cfw  = (const float*)d_in[13];
    const float* cfcb = (const float*)d_in[14];

    float* ws = (float*)d_ws;
    float* S  = ws + WS_S;
    float* Y  = ws + WS_Y;
    float* E  = ws + WS_E;
    float* out = (float*)d_out;

    hipMemsetAsync(ws, 0, (size_t)WS_E * sizeof(float), stream);  // zero S + Y
    k_build_s<<<1, 256, 0, stream>>>(ei, S);

    if (ws_size >= WS_NEED_BYTES) {
        unsigned short* xb = (unsigned short*)((char*)d_ws + XB_OFF_BYTES);
        k_cvt_x<<<800, 256, 0, stream>>>(x, (ushort8*)xb);
        k_gemm3<<<dim3(6, NKC3), 512, 0, stream>>>(xb, wa, wc, Y);
    } else {
        k_gemm_f32<<<dim3(6, NKC), 256, 0, stream>>>(x, wa, wc, Y);
    }

    k_emb<<<120, 128, 0, stream>>>(S, Y, vnr, avw, avb, cvw, cvb,
                                   acb, ccb, afcb, cfcb, E, out);
    k_heads<<<240, 128, 0, stream>>>(E, afw, cfw, out);
}

// Round 6
// 235.971 us; speedup vs baseline: 1.3869x; 1.0091x over previous
//
#include <hip/hip_runtime.h>
#include <math.h>

// ---------------- constants ----------------
// N=100 nodes, IN_C=65536, OUT_C=60, K=3 cheb, 2 heads, 1600 edges
#define KDIM    65536
#define NNODES  100
#define OUTC    60
#define YW      64          // padded col width of Y
#define YSLAB   (NNODES*YW) // 6400 floats per hk

// DMA GEMM chunking
#define BK4     64          // k per pipeline stage
#define ITERS4  8
#define SLAB4   (BK4*ITERS4)    // 512 k per block
#define NKC4    (KDIM/SLAB4)    // 128
// f32 fallback GEMM chunking
#define CHUNK   256
#define NKC     256
#define STEPS   (CHUNK/32)

// ws layout (float offsets)
#define WS_S    0           // 10000 floats
#define WS_Y    10048       // 6*6400 = 38400 floats
#define WS_E    48448       // 2*6000 = 12000 floats (zero region ends here)
// bf16 scratch (byte offsets)
#define XB_OFF_BYTES   245760ull                      // float offset 61440
#define XB_BYTES       (100ull*65536ull*2ull)         // 13107200
#define WT_OFF_BYTES   (XB_OFF_BYTES + XB_BYTES)      // 13352960
#define WT_BYTES       (6ull*60ull*65536ull*2ull)     // 47185920
#define WS_NEED_BYTES  (WT_OFF_BYTES + WT_BYTES)      // 60538880

typedef short bf16x8 __attribute__((ext_vector_type(8)));
typedef float f32x4  __attribute__((ext_vector_type(4)));
typedef unsigned short ushort8 __attribute__((ext_vector_type(8)));

__device__ inline unsigned short f2bf(float f) {
    union { float f; unsigned u; } x; x.f = f;
    unsigned r = x.u + 0x7FFFu + ((x.u >> 16) & 1u);   // RNE (finite inputs)
    return (unsigned short)(r >> 16);
}

// ---------------- kernel 1: scatter S = -D^-1/2 A D^-1/2 (S pre-zeroed) --------
__global__ __launch_bounds__(256) void k_build_s(const int* __restrict__ ei,
                                                 float* __restrict__ S) {
    __shared__ int   deg[NNODES];
    __shared__ float dinv[NNODES];
    const int t = threadIdx.x;
    if (t < NNODES) deg[t] = 0;
    __syncthreads();
    const int* src = ei;
    const int* dst = ei + 1600;
    for (int e = t; e < 1600; e += 256) atomicAdd(&deg[src[e]], 1);
    __syncthreads();
    if (t < NNODES) { int d = deg[t]; dinv[t] = (d > 0) ? rsqrtf((float)d) : 0.f; }
    __syncthreads();
    for (int e = t; e < 1600; e += 256) {
        int s = src[e], d = dst[e];
        atomicAdd(&S[d * NNODES + s], -dinv[s] * dinv[d]);
    }
}

// ---------------- pass 1a: x f32 -> bf16 (pure stream) -------------------------
__global__ __launch_bounds__(256) void k_cvt_x(const float* __restrict__ x,
                                               ushort8* __restrict__ xb) {
    int g = blockIdx.x * 256 + threadIdx.x;
    for (int i = g; i < 819200; i += 204800) {
        const float4 lo = ((const float4*)x)[2 * i];
        const float4 hi = ((const float4*)x)[2 * i + 1];
        ushort8 o;
        o[0] = f2bf(lo.x); o[1] = f2bf(lo.y); o[2] = f2bf(lo.z); o[3] = f2bf(lo.w);
        o[4] = f2bf(hi.x); o[5] = f2bf(hi.y); o[6] = f2bf(hi.z); o[7] = f2bf(hi.w);
        xb[i] = o;
    }
}

// ---------------- pass 1b: W [K][60] f32 -> W^T [60][K] bf16, LDS transpose ----
// grid (1024, 6): 64-k x 60-c tile per block. Tile is 64 full rows = contiguous.
__global__ __launch_bounds__(256) void k_cvt_w(const float* __restrict__ wa,
                                               const float* __restrict__ wc,
                                               unsigned* __restrict__ wt) {
    __shared__ unsigned short tile[64 * 61];
    const int kb = blockIdx.x, hk = blockIdx.y, t = threadIdx.x;
    const float* W = (hk < 3 ? wa : wc)
                   + (size_t)(hk % 3) * ((size_t)KDIM * OUTC)
                   + (size_t)kb * 3840;
#pragma unroll
    for (int it = 0; it < 4; ++it) {
        int i4 = t + it * 256;
        if (i4 < 960) {
            float4 v = ((const float4*)W)[i4];
            int i = i4 * 4;
            tile[(i / 60) * 61 + (i % 60)]             = f2bf(v.x);
            tile[((i+1) / 60) * 61 + ((i+1) % 60)]     = f2bf(v.y);
            tile[((i+2) / 60) * 61 + ((i+2) % 60)]     = f2bf(v.z);
            tile[((i+3) / 60) * 61 + ((i+3) % 60)]     = f2bf(v.w);
        }
    }
    __syncthreads();
#pragma unroll
    for (int it = 0; it < 8; ++it) {
        int d = t + it * 256;
        if (d < 1920) {
            int c = d >> 5, jp = d & 31;
            unsigned lo = tile[(2 * jp)     * 61 + c];
            unsigned hi = tile[(2 * jp + 1) * 61 + c];
            size_t elem = (size_t)(hk * 60 + c) * KDIM + (size_t)kb * 64 + 2 * jp;
            wt[elem >> 1] = lo | (hi << 16);
        }
    }
}

// ---------------- pass 2: DMA-pipelined bf16 MFMA GEMM -------------------------
// grid (6, 128) = 768 blocks = exactly 3/CU. block 256 = 4 waves = 4 n-tiles;
// each wave does all 7 m-tiles. K-loop: 8 iters of BK=64, double-buffered LDS
// staged entirely by global_load_lds width-16 (zero VGPR cost, 1KB/instr in
// flight). XOR chunk-swizzle on the DMA *gather* side makes the ds_read_b128
// frag reads 2-way-conflict-free while LDS writes stay lane-linear (m104).
__global__ __launch_bounds__(256) void k_gemm4(const unsigned short* __restrict__ xb,
                                               const unsigned short* __restrict__ wt,
                                               float* __restrict__ Y) {
    __shared__ unsigned short Ab[2][112 * BK4];   // 14336 B per buffer
    __shared__ unsigned short Bb[2][64 * BK4];    //  8192 B per buffer
    const int hk   = blockIdx.x;
    const int kc   = blockIdx.y;
    const int wave = threadIdx.x >> 6;
    const int lane = threadIdx.x & 63;
    const int n16  = lane & 15;
    const int quad = lane >> 4;
    const int c0   = wave * 16;
    const int kb0  = kc * SLAB4;

    auto DMA = [&](int buf, int kb) {
        // A: 14 x 1KB instrs (8 rows each); lane gathers the swizzled chunk.
        for (int j = wave; j < 14; j += 4) {
            int chunk = j * 64 + lane;
            int m  = chunk >> 3;
            int cc = (chunk & 7) ^ (m & 7);
            const unsigned short* src = xb + (size_t)min(m, NNODES - 1) * KDIM + kb + cc * 8;
            __builtin_amdgcn_global_load_lds(
                (const __attribute__((address_space(1))) void*)src,
                (__attribute__((address_space(3))) void*)&Ab[buf][j * 512], 16, 0, 0);
        }
        // B: 8 x 1KB instrs
        for (int j = wave; j < 8; j += 4) {
            int chunk = j * 64 + lane;
            int cr  = chunk >> 3;
            int kch = (chunk & 7) ^ (cr & 7);
            const unsigned short* src = wt + (size_t)(hk * 60 + min(cr, OUTC - 1)) * KDIM
                                           + kb + kch * 8;
            __builtin_amdgcn_global_load_lds(
                (const __attribute__((address_space(1))) void*)src,
                (__attribute__((address_space(3))) void*)&Bb[buf][j * 512], 16, 0, 0);
        }
    };

    DMA(0, kb0);
    f32x4 acc[7] = {};

#pragma unroll
    for (int it = 0; it < ITERS4; ++it) {
        __syncthreads();                      // vmcnt drain: DMA(it) landed
        if (it + 1 < ITERS4) DMA((it + 1) & 1, kb0 + (it + 1) * BK4);
        const unsigned short* A = Ab[it & 1];
        const unsigned short* B = Bb[it & 1];
#pragma unroll
        for (int s = 0; s < 2; ++s) {
            // swizzled chunk index — same for A and B since row&7 == n16&7
            int ch = (s * 4 + quad) ^ (n16 & 7);
            bf16x8 bfr = *(const bf16x8*)(B + (c0 + n16) * BK4 + ch * 8);
#pragma unroll
            for (int t = 0; t < 7; ++t) {
                bf16x8 afr = *(const bf16x8*)(A + (t * 16 + n16) * BK4 + ch * 8);
                acc[t] = __builtin_amdgcn_mfma_f32_16x16x32_bf16(afr, bfr, acc[t], 0, 0, 0);
            }
        }
    }

    // D layout: col = lane&15, row = quad*4 + r within 16x16 tile
    float* Yb = Y + hk * YSLAB;
#pragma unroll
    for (int t = 0; t < 7; ++t)
#pragma unroll
        for (int r = 0; r < 4; ++r) {
            int row = t * 16 + quad * 4 + r;
            if (row < NNODES)
                atomicAdd(&Yb[row * YW + c0 + n16], acc[t][r]);
        }
}

// ---------------- fallback f32 GEMM (used only if ws is too small) -------------
__global__ __launch_bounds__(256, 2) void k_gemm_f32(const float* __restrict__ x,
                                                     const float* __restrict__ wa,
                                                     const float* __restrict__ wc,
                                                     float* __restrict__ Y) {
    const int hk   = blockIdx.x;
    const int kc   = blockIdx.y;
    const int wave = threadIdx.x >> 6;
    const int lane = threadIdx.x & 63;
    const int n16  = lane & 15;
    const int quad = lane >> 4;
    const float* W = (hk < 3 ? wa : wc) + (size_t)(hk % 3) * ((size_t)KDIM * OUTC);
    const int c0   = wave * 16;
    const int cidx = min(c0 + n16, OUTC - 1);
    const int kb0  = kc * CHUNK + quad * 8;
    const float* ap[7];
#pragma unroll
    for (int t = 0; t < 7; ++t)
        ap[t] = x + (size_t)min(n16 + 16 * t, NNODES - 1) * KDIM + kb0;
    const float* bp = W + (size_t)kb0 * OUTC + cidx;
    f32x4 acc[7] = {};
#pragma unroll 2
    for (int s = 0; s < STEPS; ++s) {
        bf16x8 bfr;
        const float* q = bp + (size_t)s * 32 * OUTC;
#pragma unroll
        for (int j = 0; j < 8; ++j) bfr[j] = (short)f2bf(q[j * OUTC]);
#pragma unroll
        for (int t = 0; t < 7; ++t) {
            const float* p = ap[t] + s * 32;
            float4 lo = *(const float4*)p;
            float4 hi = *(const float4*)(p + 4);
            bf16x8 afr;
            afr[0] = (short)f2bf(lo.x); afr[1] = (short)f2bf(lo.y);
            afr[2] = (short)f2bf(lo.z); afr[3] = (short)f2bf(lo.w);
            afr[4] = (short)f2bf(hi.x); afr[5] = (short)f2bf(hi.y);
            afr[6] = (short)f2bf(hi.z); afr[7] = (short)f2bf(hi.w);
            acc[t] = __builtin_amdgcn_mfma_f32_16x16x32_bf16(afr, bfr, acc[t], 0, 0, 0);
        }
    }
    float* Yb = Y + hk * YSLAB;
#pragma unroll
    for (int t = 0; t < 7; ++t)
#pragma unroll
        for (int r = 0; r < 4; ++r) {
            int row = t * 16 + quad * 4 + r;
            if (row < NNODES)
                atomicAdd(&Yb[row * YW + c0 + n16], acc[t][r]);
        }
}

// ---------------- kernel 3: emb = tanh(Y0 + S Y1 + 2 S(S Y2) - Y2 + b) + vnr ----
__global__ __launch_bounds__(128) void k_emb(const float* __restrict__ S,
                                             const float* __restrict__ Y,
                                             const float* __restrict__ vnr,
                                             const float* __restrict__ avw,
                                             const float* __restrict__ avb,
                                             const float* __restrict__ cvw,
                                             const float* __restrict__ cvb,
                                             const float* __restrict__ acb,
                                             const float* __restrict__ ccb,
                                             const float* __restrict__ afcb,
                                             const float* __restrict__ cfcb,
                                             float* __restrict__ E,
                                             float* __restrict__ out) {
    __shared__ float Sp[NNODES * 101];
    __shared__ float y0[NNODES], y1[NNODES], y2[NNODES], t2[NNODES];
    const int b = blockIdx.x, head = b / OUTC, c = b % OUTC;
    const int t = threadIdx.x;

    for (int i = t; i < NNODES * NNODES; i += 128)
        Sp[(i / NNODES) * 101 + (i % NNODES)] = S[i];
    const float* Yh = Y + (size_t)head * 3 * YSLAB;
    if (t < NNODES) {
        y0[t] = Yh[t * YW + c];
        y1[t] = Yh[YSLAB + t * YW + c];
        y2[t] = Yh[2 * YSLAB + t * YW + c];
    }
    if (b == 0 && t < 101) out[t] = (t < 100) ? afcb[t] : cfcb[0];
    __syncthreads();

    float z1 = 0.f, s2 = 0.f;
    if (t < NNODES) {
        const float* sr = Sp + t * 101;
        for (int m = 0; m < NNODES; ++m) { z1 += sr[m] * y1[m]; s2 += sr[m] * y2[m]; }
        t2[t] = s2;
    }
    __syncthreads();
    if (t < NNODES) {
        const float* sr = Sp + t * 101;
        float t3 = 0.f;
        for (int m = 0; m < NNODES; ++m) t3 += sr[m] * t2[m];
        const float* cb = head ? ccb : acb;
        const float* vw = head ? cvw : avw;
        const float* vb = head ? cvb : avb;
        float u  = y0[t] + z1 + 2.f * t3 - y2[t] + cb[c];
        float vs = vnr[0] * vw[c]        + vb[c]
                 + vnr[1] * vw[OUTC + c] + vb[OUTC + c]
                 + vnr[2] * vw[2*OUTC+c] + vb[2*OUTC+c];
        E[head * (NNODES * OUTC) + t * OUTC + c] = tanhf(u) + vs;
    }
}

// ---------------- kernel 4: heads — grid 240, 25 flat rows per block -----------
__global__ __launch_bounds__(128) void k_heads(const float* __restrict__ E,
                                               const float* __restrict__ afw,
                                               const float* __restrict__ cfw,
                                               float* __restrict__ out) {
    __shared__ float ea[25], ec[25];
    const int b = blockIdx.x, t = threadIdx.x;
    const int f0 = b * 25;
    if (t < 25) {
        ea[t] = E[f0 + t];
        ec[t] = E[NNODES * OUTC + f0 + t];
    }
    __syncthreads();
    if (t < 100) {
        float s = 0.f;
#pragma unroll
        for (int i = 0; i < 25; ++i) s += ea[i] * afw[(size_t)(f0 + i) * 100 + t];
        atomicAdd(&out[t], s);
    } else if (t == 100) {
        float s = 0.f;
#pragma unroll
        for (int i = 0; i < 25; ++i) s += ec[i] * cfw[f0 + i];
        atomicAdd(&out[100], s);
    }
}

// ---------------- launch ----------------
extern "C" void kernel_launch(void* const* d_in, const int* in_sizes, int n_in,
                              void* d_out, int out_size, void* d_ws, size_t ws_size,
                              hipStream_t stream) {
    const float* x    = (const float*)d_in[0];
    const int*   ei   = (const int*)  d_in[1];
    const float* vnr  = (const float*)d_in[2];
    const float* wa   = (const float*)d_in[3];
    const float* acb  = (const float*)d_in[4];
    const float* wc   = (const float*)d_in[5];
    const float* ccb  = (const float*)d_in[6];
    const float* avw  = (const float*)d_in[7];
    const float* avb  = (const float*)d_in[8];
    const float* cvw  = (const float*)d_in[9];
    const float* cvb  = (const float*)d_in[10];
    const float* afw  = (const float*)d_in[11];
    const float* afcb = (const float*)d_in[12];
    const float* cfw  = (const float*)d_in[13];
    const float* cfcb = (const float*)d_in[14];

    float* ws = (float*)d_ws;
    float* S  = ws + WS_S;
    float* Y  = ws + WS_Y;
    float* E  = ws + WS_E;
    float* out = (float*)d_out;

    hipMemsetAsync(ws, 0, (size_t)WS_E * sizeof(float), stream);  // zero S + Y
    k_build_s<<<1, 256, 0, stream>>>(ei, S);

    if (ws_size >= WS_NEED_BYTES) {
        unsigned short* xb = (unsigned short*)((char*)d_ws + XB_OFF_BYTES);
        unsigned*       wt = (unsigned*)((char*)d_ws + WT_OFF_BYTES);
        k_cvt_x<<<800, 256, 0, stream>>>(x, (ushort8*)xb);
        k_cvt_w<<<dim3(1024, 6), 256, 0, stream>>>(wa, wc, wt);
        k_gemm4<<<dim3(6, NKC4), 256, 0, stream>>>(xb, (const unsigned short*)wt, Y);
    } else {
        k_gemm_f32<<<dim3(6, NKC), 256, 0, stream>>>(x, wa, wc, Y);
    }

    k_emb<<<120, 128, 0, stream>>>(S, Y, vnr, avw, avb, cvw, cvb,
                                   acb, ccb, afcb, cfcb, E, out);
    k_heads<<<240, 128, 0, stream>>>(E, afw, cfw, out);
}

// Round 7
// 214.243 us; speedup vs baseline: 1.5276x; 1.1014x over previous
//
#include <hip/hip_runtime.h>
#include <math.h>

// ---------------- constants ----------------
// N=100 nodes, IN_C=65536, OUT_C=60, K=3 cheb, 2 heads, 1600 edges
#define KDIM    65536
#define NNODES  100
#define OUTC    60
#define YW      64          // padded col width of Y
#define YSLAB   (NNODES*YW) // 6400 floats per hk

// DMA GEMM chunking
#define BK5     64              // k per pipeline stage
#define ITERS5  8
#define SLAB5   (BK5*ITERS5)    // 512 k per block
#define NKC5    (KDIM/SLAB5)    // 128
// f32 fallback GEMM chunking
#define CHUNK   256
#define NKC     256
#define STEPS   (CHUNK/32)

// ws layout (float offsets)
#define WS_S    0           // 10000 floats
#define WS_Y    10048       // 6*6400 = 38400 floats
#define WS_E    48448       // 2*6000 = 12000 floats (zero region ends here)
// bf16 x scratch (byte offsets)
#define XB_OFF_BYTES   245760ull                      // float offset 61440
#define XB_BYTES       (100ull*65536ull*2ull)         // 13107200
#define WS_NEED_BYTES  (XB_OFF_BYTES + XB_BYTES)      // 13352960

typedef short bf16x8 __attribute__((ext_vector_type(8)));
typedef float f32x4  __attribute__((ext_vector_type(4)));
typedef unsigned short ushort8 __attribute__((ext_vector_type(8)));

__device__ inline unsigned short f2bf(float f) {
    union { float f; unsigned u; } x; x.f = f;
    unsigned r = x.u + 0x7FFFu + ((x.u >> 16) & 1u);   // RNE (finite inputs)
    return (unsigned short)(r >> 16);
}

// ---------------- kernel 1: scatter S = -D^-1/2 A D^-1/2 (S pre-zeroed) --------
__global__ __launch_bounds__(256) void k_build_s(const int* __restrict__ ei,
                                                 float* __restrict__ S) {
    __shared__ int   deg[NNODES];
    __shared__ float dinv[NNODES];
    const int t = threadIdx.x;
    if (t < NNODES) deg[t] = 0;
    __syncthreads();
    const int* src = ei;
    const int* dst = ei + 1600;
    for (int e = t; e < 1600; e += 256) atomicAdd(&deg[src[e]], 1);
    __syncthreads();
    if (t < NNODES) { int d = deg[t]; dinv[t] = (d > 0) ? rsqrtf((float)d) : 0.f; }
    __syncthreads();
    for (int e = t; e < 1600; e += 256) {
        int s = src[e], d = dst[e];
        atomicAdd(&S[d * NNODES + s], -dinv[s] * dinv[d]);
    }
}

// ---------------- pass 1: x f32 -> bf16 (pure stream) --------------------------
__global__ __launch_bounds__(256) void k_cvt_x(const float* __restrict__ x,
                                               ushort8* __restrict__ xb) {
    int g = blockIdx.x * 256 + threadIdx.x;
    for (int i = g; i < 819200; i += 204800) {
        const float4 lo = ((const float4*)x)[2 * i];
        const float4 hi = ((const float4*)x)[2 * i + 1];
        ushort8 o;
        o[0] = f2bf(lo.x); o[1] = f2bf(lo.y); o[2] = f2bf(lo.z); o[3] = f2bf(lo.w);
        o[4] = f2bf(hi.x); o[5] = f2bf(hi.y); o[6] = f2bf(hi.z); o[7] = f2bf(hi.w);
        xb[i] = o;
    }
}

// ---------------- pass 2: single-pass DMA GEMM (fused W convert) ---------------
// grid (6, 128). block 256 = 4 waves = 4 n-tiles; each wave does all 7 m-tiles.
// K-loop: 8 iters of BK=64, double-buffered LDS, both operands staged by
// global_load_lds width-16 (zero VGPR cost, 1KB/instr in flight):
//   A: bf16 x rows, chunk-XOR-swizzled image -> ds_read_b128 frags (2-way free).
//   W: raw f32 [64][60] chunk = 15360 contiguous bytes = 15 DMA instrs;
//      B-frags via quad-rotated ds_read_b32 (4 disjoint 16-bank windows ->
//      2-way = free) + f2bf in VALU, hidden under the DMA stream.
__global__ __launch_bounds__(256) void k_gemm5(const unsigned short* __restrict__ xb,
                                               const float* __restrict__ wa,
                                               const float* __restrict__ wc,
                                               float* __restrict__ Y) {
    __shared__ unsigned short Ab[2][112 * BK5];   // 14336 B per buffer
    __shared__ float          Wf[2][BK5 * OUTC];  // 15360 B per buffer
    const int hk   = blockIdx.x;
    const int kc   = blockIdx.y;
    const int wave = threadIdx.x >> 6;
    const int lane = threadIdx.x & 63;
    const int n16  = lane & 15;
    const int quad = lane >> 4;
    const int c0   = wave * 16;
    const int cidx = min(c0 + n16, OUTC - 1);   // cols 60..63 junk -> pad cols of Y
    const int kb0  = kc * SLAB5;

    const float* Wg = (hk < 3 ? wa : wc) + (size_t)(hk % 3) * ((size_t)KDIM * OUTC);

    auto DMA = [&](int buf, int kb) {
        // A: 14 x 1KB instrs (8 bf16 rows each); lane gathers its swizzled chunk.
        for (int j = wave; j < 14; j += 4) {
            int chunk = j * 64 + lane;
            int m  = chunk >> 3;
            int cc = (chunk & 7) ^ (m & 7);
            const unsigned short* src = xb + (size_t)min(m, NNODES - 1) * KDIM + kb + cc * 8;
            __builtin_amdgcn_global_load_lds(
                (const __attribute__((address_space(1))) void*)src,
                (__attribute__((address_space(3))) void*)&Ab[buf][j * 512], 16, 0, 0);
        }
        // W: 15 x 1KB instrs, fully contiguous [64][60] f32 chunk.
        const float* wsrc = Wg + (size_t)kb * OUTC;
        for (int j = wave; j < 15; j += 4) {
            __builtin_amdgcn_global_load_lds(
                (const __attribute__((address_space(1))) void*)(wsrc + j * 256 + lane * 4),
                (__attribute__((address_space(3))) void*)&Wf[buf][j * 256], 16, 0, 0);
        }
    };

    DMA(0, kb0);
    f32x4 acc[7] = {};

#pragma unroll
    for (int it = 0; it < ITERS5; ++it) {
        __syncthreads();                      // vmcnt drain: DMA(it) landed
        if (it + 1 < ITERS5) DMA((it + 1) & 1, kb0 + (it + 1) * BK5);
        const unsigned short* A = Ab[it & 1];
        const float*          B = Wf[it & 1];
#pragma unroll
        for (int s = 0; s < 2; ++s) {
            // B-frag: lane (n16,quad) needs W[s*32+quad*8+j][cidx], j=0..7.
            // quad-rotated j order -> 4 disjoint 16-bank windows (2-way = free).
            bf16x8 bfr;
#pragma unroll
            for (int j = 0; j < 8; ++j) {
                int jj = (j + quad * 2) & 7;
                bfr[jj] = (short)f2bf(B[(s * 32 + quad * 8 + jj) * OUTC + cidx]);
            }
            // A-frag: swizzled chunk index (row&7 == n16&7)
            int ch = (s * 4 + quad) ^ (n16 & 7);
#pragma unroll
            for (int t = 0; t < 7; ++t) {
                bf16x8 afr = *(const bf16x8*)(A + (t * 16 + n16) * BK5 + ch * 8);
                acc[t] = __builtin_amdgcn_mfma_f32_16x16x32_bf16(afr, bfr, acc[t], 0, 0, 0);
            }
        }
    }

    // D layout: col = lane&15, row = quad*4 + r within 16x16 tile
    float* Yb = Y + hk * YSLAB;
#pragma unroll
    for (int t = 0; t < 7; ++t)
#pragma unroll
        for (int r = 0; r < 4; ++r) {
            int row = t * 16 + quad * 4 + r;
            if (row < NNODES)
                atomicAdd(&Yb[row * YW + c0 + n16], acc[t][r]);
        }
}

// ---------------- fallback f32 GEMM (used only if ws is too small) -------------
__global__ __launch_bounds__(256, 2) void k_gemm_f32(const float* __restrict__ x,
                                                     const float* __restrict__ wa,
                                                     const float* __restrict__ wc,
                                                     float* __restrict__ Y) {
    const int hk   = blockIdx.x;
    const int kc   = blockIdx.y;
    const int wave = threadIdx.x >> 6;
    const int lane = threadIdx.x & 63;
    const int n16  = lane & 15;
    const int quad = lane >> 4;
    const float* W = (hk < 3 ? wa : wc) + (size_t)(hk % 3) * ((size_t)KDIM * OUTC);
    const int c0   = wave * 16;
    const int cidx = min(c0 + n16, OUTC - 1);
    const int kb0  = kc * CHUNK + quad * 8;
    const float* ap[7];
#pragma unroll
    for (int t = 0; t < 7; ++t)
        ap[t] = x + (size_t)min(n16 + 16 * t, NNODES - 1) * KDIM + kb0;
    const float* bp = W + (size_t)kb0 * OUTC + cidx;
    f32x4 acc[7] = {};
#pragma unroll 2
    for (int s = 0; s < STEPS; ++s) {
        bf16x8 bfr;
        const float* q = bp + (size_t)s * 32 * OUTC;
#pragma unroll
        for (int j = 0; j < 8; ++j) bfr[j] = (short)f2bf(q[j * OUTC]);
#pragma unroll
        for (int t = 0; t < 7; ++t) {
            const float* p = ap[t] + s * 32;
            float4 lo = *(const float4*)p;
            float4 hi = *(const float4*)(p + 4);
            bf16x8 afr;
            afr[0] = (short)f2bf(lo.x); afr[1] = (short)f2bf(lo.y);
            afr[2] = (short)f2bf(lo.z); afr[3] = (short)f2bf(lo.w);
            afr[4] = (short)f2bf(hi.x); afr[5] = (short)f2bf(hi.y);
            afr[6] = (short)f2bf(hi.z); afr[7] = (short)f2bf(hi.w);
            acc[t] = __builtin_amdgcn_mfma_f32_16x16x32_bf16(afr, bfr, acc[t], 0, 0, 0);
        }
    }
    float* Yb = Y + hk * YSLAB;
#pragma unroll
    for (int t = 0; t < 7; ++t)
#pragma unroll
        for (int r = 0; r < 4; ++r) {
            int row = t * 16 + quad * 4 + r;
            if (row < NNODES)
                atomicAdd(&Yb[row * YW + c0 + n16], acc[t][r]);
        }
}

// ---------------- kernel 3: emb = tanh(Y0 + S Y1 + 2 S(S Y2) - Y2 + b) + vnr ----
__global__ __launch_bounds__(128) void k_emb(const float* __restrict__ S,
                                             const float* __restrict__ Y,
                                             const float* __restrict__ vnr,
                                             const float* __restrict__ avw,
                                             const float* __restrict__ avb,
                                             const float* __restrict__ cvw,
                                             const float* __restrict__ cvb,
                                             const float* __restrict__ acb,
                                             const float* __restrict__ ccb,
                                             const float* __restrict__ afcb,
                                             const float* __restrict__ cfcb,
                                             float* __restrict__ E,
                                             float* __restrict__ out) {
    __shared__ float Sp[NNODES * 101];
    __shared__ float y0[NNODES], y1[NNODES], y2[NNODES], t2[NNODES];
    const int b = blockIdx.x, head = b / OUTC, c = b % OUTC;
    const int t = threadIdx.x;

    for (int i = t; i < NNODES * NNODES; i += 128)
        Sp[(i / NNODES) * 101 + (i % NNODES)] = S[i];
    const float* Yh = Y + (size_t)head * 3 * YSLAB;
    if (t < NNODES) {
        y0[t] = Yh[t * YW + c];
        y1[t] = Yh[YSLAB + t * YW + c];
        y2[t] = Yh[2 * YSLAB + t * YW + c];
    }
    if (b == 0 && t < 101) out[t] = (t < 100) ? afcb[t] : cfcb[0];
    __syncthreads();

    float z1 = 0.f, s2 = 0.f;
    if (t < NNODES) {
        const float* sr = Sp + t * 101;
        for (int m = 0; m < NNODES; ++m) { z1 += sr[m] * y1[m]; s2 += sr[m] * y2[m]; }
        t2[t] = s2;
    }
    __syncthreads();
    if (t < NNODES) {
        const float* sr = Sp + t * 101;
        float t3 = 0.f;
        for (int m = 0; m < NNODES; ++m) t3 += sr[m] * t2[m];
        const float* cb = head ? ccb : acb;
        const float* vw = head ? cvw : avw;
        const float* vb = head ? cvb : avb;
        float u  = y0[t] + z1 + 2.f * t3 - y2[t] + cb[c];
        float vs = vnr[0] * vw[c]        + vb[c]
                 + vnr[1] * vw[OUTC + c] + vb[OUTC + c]
                 + vnr[2] * vw[2*OUTC+c] + vb[2*OUTC+c];
        E[head * (NNODES * OUTC) + t * OUTC + c] = tanhf(u) + vs;
    }
}

// ---------------- kernel 4: heads — grid 240, 25 flat rows per block -----------
__global__ __launch_bounds__(128) void k_heads(const float* __restrict__ E,
                                               const float* __restrict__ afw,
                                               const float* __restrict__ cfw,
                                               float* __restrict__ out) {
    __shared__ float ea[25], ec[25];
    const int b = blockIdx.x, t = threadIdx.x;
    const int f0 = b * 25;
    if (t < 25) {
        ea[t] = E[f0 + t];
        ec[t] = E[NNODES * OUTC + f0 + t];
    }
    __syncthreads();
    if (t < 100) {
        float s = 0.f;
#pragma unroll
        for (int i = 0; i < 25; ++i) s += ea[i] * afw[(size_t)(f0 + i) * 100 + t];
        atomicAdd(&out[t], s);
    } else if (t == 100) {
        float s = 0.f;
#pragma unroll
        for (int i = 0; i < 25; ++i) s += ec[i] * cfw[f0 + i];
        atomicAdd(&out[100], s);
    }
}

// ---------------- launch ----------------
extern "C" void kernel_launch(void* const* d_in, const int* in_sizes, int n_in,
                              void* d_out, int out_size, void* d_ws, size_t ws_size,
                              hipStream_t stream) {
    const float* x    = (const float*)d_in[0];
    const int*   ei   = (const int*)  d_in[1];
    const float* vnr  = (const float*)d_in[2];
    const float* wa   = (const float*)d_in[3];
    const float* acb  = (const float*)d_in[4];
    const float* wc   = (const float*)d_in[5];
    const float* ccb  = (const float*)d_in[6];
    const float* avw  = (const float*)d_in[7];
    const float* avb  = (const float*)d_in[8];
    const float* cvw  = (const float*)d_in[9];
    const float* cvb  = (const float*)d_in[10];
    const float* afw  = (const float*)d_in[11];
    const float* afcb = (const float*)d_in[12];
    const float* cfw  = (const float*)d_in[13];
    const float* cfcb = (const float*)d_in[14];

    float* ws = (float*)d_ws;
    float* S  = ws + WS_S;
    float* Y  = ws + WS_Y;
    float* E  = ws + WS_E;
    float* out = (float*)d_out;

    hipMemsetAsync(ws, 0, (size_t)WS_E * sizeof(float), stream);  // zero S + Y
    k_build_s<<<1, 256, 0, stream>>>(ei, S);

    if (ws_size >= WS_NEED_BYTES) {
        unsigned short* xb = (unsigned short*)((char*)d_ws + XB_OFF_BYTES);
        k_cvt_x<<<800, 256, 0, stream>>>(x, (ushort8*)xb);
        k_gemm5<<<dim3(6, NKC5), 256, 0, stream>>>(xb, wa, wc, Y);
    } else {
        k_gemm_f32<<<dim3(6, NKC), 256, 0, stream>>>(x, wa, wc, Y);
    }

    k_emb<<<120, 128, 0, stream>>>(S, Y, vnr, avw, avb, cvw, cvb,
                                   acb, ccb, afcb, cfcb, E, out);
    k_heads<<<240, 128, 0, stream>>>(E, afw, cfw, out);
}